// Round 1
// baseline (1038.359 us; speedup 1.0000x reference)
//
#include <hip/hip_runtime.h>
#include <cstddef>

#define B_     4
#define NTOK   1024
#define DMODEL 768
#define NH     12
#define HD     64
#define IMGC   256
#define NPIX   1024

// workspace layout (float offsets)
#define WQ0  0
#define WK0  3145728
#define WV0  6291456
#define WY1  9437184
#define WY2  10485760
#define WSC  13631488
#define WSH  13632256

// ---------------- K1: QKV GEMM  [4096,768] @ [768,2304] -> q/k/v [b,h,n,hd]
__global__ __launch_bounds__(256) void k_qkv_gemm(const float* __restrict__ X,
                                                  const float* __restrict__ W,
                                                  float* __restrict__ q,
                                                  float* __restrict__ k,
                                                  float* __restrict__ v) {
  __shared__ __align__(16) float As[64][18];
  __shared__ __align__(16) float Bt[64][18];   // B transposed: [col][kk]
  const int t  = threadIdx.x;
  const int tx = t & 15, ty = t >> 4;
  const int m0 = blockIdx.y * 64;
  const int n0 = blockIdx.x * 64;
  const int lcol = t & 63, lrow4 = (t >> 6) << 2;
  const int ar = t >> 2, ac = (t & 3) << 2;
  float acc[4][4] = {};
  for (int k0 = 0; k0 < 768; k0 += 16) {
    float4 a4 = *(const float4*)&X[(size_t)(m0 + ar) * 768 + k0 + ac];
    *(float2*)&As[ar][ac]     = make_float2(a4.x, a4.y);
    *(float2*)&As[ar][ac + 2] = make_float2(a4.z, a4.w);
#pragma unroll
    for (int rep = 0; rep < 4; rep++) {
      int row = lrow4 + rep;
      Bt[lcol][row] = W[(size_t)(k0 + row) * 2304 + n0 + lcol];
    }
    __syncthreads();
#pragma unroll
    for (int kk = 0; kk < 16; kk += 2) {
      float2 a[4], b[4];
#pragma unroll
      for (int i = 0; i < 4; i++) a[i] = *(const float2*)&As[ty + 16 * i][kk];
#pragma unroll
      for (int j = 0; j < 4; j++) b[j] = *(const float2*)&Bt[tx + 16 * j][kk];
#pragma unroll
      for (int i = 0; i < 4; i++)
#pragma unroll
        for (int j = 0; j < 4; j++) {
          acc[i][j] = fmaf(a[i].x, b[j].x, acc[i][j]);
          acc[i][j] = fmaf(a[i].y, b[j].y, acc[i][j]);
        }
    }
    __syncthreads();
  }
#pragma unroll
  for (int i = 0; i < 4; i++) {
    const int m = m0 + ty + 16 * i;
    const int bb = m >> 10, nn = m & 1023;
#pragma unroll
    for (int j = 0; j < 4; j++) {
      const int ng = n0 + tx + 16 * j;
      const int which = ng / 768;
      const int c = ng - which * 768;
      const int head = c >> 6, dim = c & 63;
      float* dst = which == 0 ? q : (which == 1 ? k : v);
      dst[((size_t)((bb * NH + head) << 10) + nn) * 64 + dim] = acc[i][j];
    }
  }
}

// ---------------- K2: flash attention, fp32. grid(48 bh, 32 qtiles), 256 thr
__global__ __launch_bounds__(256) void k_attn(const float* __restrict__ q,
                                              const float* __restrict__ k,
                                              const float* __restrict__ v,
                                              const float* __restrict__ dm,
                                              float* __restrict__ out0) {
  __shared__ __align__(16) float Qs[32][66];
  __shared__ __align__(16) float Ks[64][66];
  __shared__ __align__(16) float Vt[64][66];   // V transposed: [dim][kcol]
  __shared__ __align__(16) float Ss[32][66];
  __shared__ float rowm[32], rowl[32], alpha_s[32], tmax[32], tsum[32];
  const int bh = blockIdx.x;       // b*12+h
  const int qt = blockIdx.y;       // 0..31
  const int t  = threadIdx.x;
  const int tx = t & 31, ty = t >> 5;
  const size_t hbase = (size_t)bh << 16;        // 1024*64
  const float* qp = q + hbase;
  const float* kp = k + hbase;
  const float* vp = v + hbase;
  const float* mp = dm + ((size_t)bh << 20) + ((size_t)(qt * 32) << 10);

  for (int idx = t; idx < 32 * 16; idx += 256) {    // load+prescale Q
    int r = idx >> 4, c4 = (idx & 15) << 2;
    float4 qv = *(const float4*)&qp[((size_t)(qt * 32 + r) << 6) + c4];
    Qs[r][c4]     = qv.x * 0.125f;
    Qs[r][c4 + 1] = qv.y * 0.125f;
    Qs[r][c4 + 2] = qv.z * 0.125f;
    Qs[r][c4 + 3] = qv.w * 0.125f;
  }
  if (t < 32) { rowm[t] = -INFINITY; rowl[t] = 0.0f; }
  float O[4][2] = {};

  for (int kt = 0; kt < 16; kt++) {
    __syncthreads();   // Q ready / prev tile consumed
    for (int idx = t; idx < 64 * 16; idx += 256) {
      int r = idx >> 4, c4 = (idx & 15) << 2;
      float4 kv = *(const float4*)&kp[((size_t)(kt * 64 + r) << 6) + c4];
      *(float2*)&Ks[r][c4]     = make_float2(kv.x, kv.y);
      *(float2*)&Ks[r][c4 + 2] = make_float2(kv.z, kv.w);
      float4 vv = *(const float4*)&vp[((size_t)(kt * 64 + r) << 6) + c4];
      Vt[c4][r] = vv.x; Vt[c4 + 1][r] = vv.y; Vt[c4 + 2][r] = vv.z; Vt[c4 + 3][r] = vv.w;
    }
    __syncthreads();

    float sv[4][2];
    {
      float s[4][2] = {};
#pragma unroll
      for (int kk = 0; kk < 64; kk += 2) {
        float2 a[4], b2[2];
#pragma unroll
        for (int i = 0; i < 4; i++) a[i] = *(const float2*)&Qs[ty + 8 * i][kk];
#pragma unroll
        for (int j = 0; j < 2; j++) b2[j] = *(const float2*)&Ks[tx + 32 * j][kk];
#pragma unroll
        for (int i = 0; i < 4; i++)
#pragma unroll
          for (int j = 0; j < 2; j++) {
            s[i][j] = fmaf(a[i].x, b2[j].x, s[i][j]);
            s[i][j] = fmaf(a[i].y, b2[j].y, s[i][j]);
          }
      }
#pragma unroll
      for (int i = 0; i < 4; i++) {
        int r = ty + 8 * i;
#pragma unroll
        for (int j = 0; j < 2; j++) {
          int c = tx + 32 * j;
          float md = mp[((size_t)r << 10) + kt * 64 + c];
          sv[i][j] = s[i][j] + (md < 0.1f ? -1e12f : 0.0f);
        }
      }
    }
    // per-row tile max (32-lane groups = half-wave, xor masks stay inside)
#pragma unroll
    for (int i = 0; i < 4; i++) {
      float pm = fmaxf(sv[i][0], sv[i][1]);
#pragma unroll
      for (int off = 1; off < 32; off <<= 1) pm = fmaxf(pm, __shfl_xor(pm, off));
      if (tx == 0) tmax[ty + 8 * i] = pm;
    }
    __syncthreads();
    if (t < 32) {
      float mo = rowm[t];
      float mn = fmaxf(mo, tmax[t]);
      rowm[t] = mn;
      alpha_s[t] = __expf(mo - mn);
    }
    __syncthreads();
#pragma unroll
    for (int i = 0; i < 4; i++) {
      int r = ty + 8 * i;
      float m = rowm[r];
      float p0v = __expf(sv[i][0] - m);
      float p1v = __expf(sv[i][1] - m);
      Ss[r][tx]      = p0v;
      Ss[r][tx + 32] = p1v;
      float ps = p0v + p1v;
#pragma unroll
      for (int off = 1; off < 32; off <<= 1) ps += __shfl_xor(ps, off);
      if (tx == 0) tsum[r] = ps;
      float al = alpha_s[r];
      O[i][0] *= al; O[i][1] *= al;
    }
    __syncthreads();
    if (t < 32) rowl[t] = rowl[t] * alpha_s[t] + tsum[t];
    // PV: O[r][dim] += sum_c P[r][c] * V[c][dim]
#pragma unroll
    for (int c = 0; c < 64; c += 2) {
      float2 p2[4], v2[2];
#pragma unroll
      for (int i = 0; i < 4; i++) p2[i] = *(const float2*)&Ss[ty + 8 * i][c];
#pragma unroll
      for (int j = 0; j < 2; j++) v2[j] = *(const float2*)&Vt[tx + 32 * j][c];
#pragma unroll
      for (int i = 0; i < 4; i++)
#pragma unroll
        for (int j = 0; j < 2; j++) {
          O[i][j] = fmaf(p2[i].x, v2[j].x, O[i][j]);
          O[i][j] = fmaf(p2[i].y, v2[j].y, O[i][j]);
        }
    }
  }
  __syncthreads();
  const int bb = bh / NH, hh = bh % NH;
#pragma unroll
  for (int i = 0; i < 4; i++) {
    int r = ty + 8 * i;
    float inv = 1.0f / rowl[r];
#pragma unroll
    for (int j = 0; j < 2; j++) {
      size_t a = ((size_t)((bb << 10) + qt * 32 + r)) * DMODEL + hh * 64 + tx + 32 * j;
      out0[a] = O[i][j] * inv;
    }
  }
}

// ---------------- K3: depthwise 3x3 'SAME'
__global__ __launch_bounds__(256) void k_dwconv(const float* __restrict__ y,
                                                const float* __restrict__ w1,
                                                float* __restrict__ y1) {
  const int bc = blockIdx.x;           // b*256 + c
  const int c = bc & 255;
  const float* yin = y + (size_t)bc * NPIX;
  float* yout = y1 + (size_t)bc * NPIX;
  float w[9];
#pragma unroll
  for (int i = 0; i < 9; i++) w[i] = w1[c * 9 + i];
  const int t = threadIdx.x;
#pragma unroll
  for (int rep = 0; rep < 4; rep++) {
    int px = t + rep * 256;
    int yy = px >> 5, xx = px & 31;
    float acc = 0.0f;
#pragma unroll
    for (int dy = -1; dy <= 1; dy++) {
      int sy = yy + dy;
      if (sy < 0 || sy > 31) continue;
#pragma unroll
      for (int dx = -1; dx <= 1; dx++) {
        int sx = xx + dx;
        if (sx < 0 || sx > 31) continue;
        acc = fmaf(yin[(sy << 5) + sx], w[(dy + 1) * 3 + dx + 1], acc);
      }
    }
    yout[px] = acc;
  }
}

// ---------------- K4: 1x1 conv = per-batch GEMM W2[768,256] @ Y1[256,1024]
__global__ __launch_bounds__(256) void k_conv1x1(const float* __restrict__ W2,
                                                 const float* __restrict__ Y1,
                                                 float* __restrict__ Y2) {
  __shared__ __align__(16) float As[64][18];
  __shared__ __align__(16) float Bt[64][18];
  const int t  = threadIdx.x;
  const int tx = t & 15, ty = t >> 4;
  const int n0 = blockIdx.x * 64;
  const int m0 = blockIdx.y * 64;
  const int bb = blockIdx.z;
  const float* Bb = Y1 + (size_t)bb * IMGC * NPIX;
  const int lcol = t & 63, lrow4 = (t >> 6) << 2;
  const int ar = t >> 2, ac = (t & 3) << 2;
  float acc[4][4] = {};
  for (int k0 = 0; k0 < 256; k0 += 16) {
    float4 a4 = *(const float4*)&W2[(size_t)(m0 + ar) * 256 + k0 + ac];
    *(float2*)&As[ar][ac]     = make_float2(a4.x, a4.y);
    *(float2*)&As[ar][ac + 2] = make_float2(a4.z, a4.w);
#pragma unroll
    for (int rep = 0; rep < 4; rep++) {
      int row = lrow4 + rep;
      Bt[lcol][row] = Bb[(size_t)(k0 + row) * 1024 + n0 + lcol];
    }
    __syncthreads();
#pragma unroll
    for (int kk = 0; kk < 16; kk += 2) {
      float2 a[4], b[4];
#pragma unroll
      for (int i = 0; i < 4; i++) a[i] = *(const float2*)&As[ty + 16 * i][kk];
#pragma unroll
      for (int j = 0; j < 4; j++) b[j] = *(const float2*)&Bt[tx + 16 * j][kk];
#pragma unroll
      for (int i = 0; i < 4; i++)
#pragma unroll
        for (int j = 0; j < 4; j++) {
          acc[i][j] = fmaf(a[i].x, b[j].x, acc[i][j]);
          acc[i][j] = fmaf(a[i].y, b[j].y, acc[i][j]);
        }
    }
    __syncthreads();
  }
#pragma unroll
  for (int i = 0; i < 4; i++) {
    int oc = m0 + ty + 16 * i;
#pragma unroll
    for (int j = 0; j < 4; j++) {
      int p = n0 + tx + 16 * j;
      Y2[((size_t)(bb * DMODEL + oc) << 10) + p] = acc[i][j];
    }
  }
}

// ---------------- K5: BN train stats -> scale/shift per channel
__global__ __launch_bounds__(256) void k_bnstats(const float* __restrict__ y2,
                                                 const float* __restrict__ gamma,
                                                 const float* __restrict__ beta,
                                                 float* __restrict__ scale,
                                                 float* __restrict__ shift) {
  const int c = blockIdx.x;
  const int t = threadIdx.x;
  float s = 0.0f, sq = 0.0f;
  for (int idx = t; idx < 4096; idx += 256) {
    int bb = idx >> 10, p = idx & 1023;
    float val = y2[((size_t)(bb * DMODEL + c) << 10) + p];
    s += val; sq = fmaf(val, val, sq);
  }
#pragma unroll
  for (int off = 32; off > 0; off >>= 1) {
    s += __shfl_down(s, off);
    sq += __shfl_down(sq, off);
  }
  __shared__ float red[8];
  const int wid = t >> 6, lid = t & 63;
  if (lid == 0) { red[wid] = s; red[4 + wid] = sq; }
  __syncthreads();
  if (t == 0) {
    float S = red[0] + red[1] + red[2] + red[3];
    float SQ = red[4] + red[5] + red[6] + red[7];
    float mean = S * (1.0f / 4096.0f);
    float var = SQ * (1.0f / 4096.0f) - mean * mean;
    float rstd = rsqrtf(var + 1e-5f);
    float sc = gamma[c] * rstd;
    scale[c] = sc;
    shift[c] = fmaf(-mean, sc, beta[c]);
  }
}

// ---------------- K6: BN+ReLU -> out1, LDS-transpose add into out0
__global__ __launch_bounds__(256) void k_bnfuse(const float* __restrict__ y2,
                                                const float* __restrict__ scale,
                                                const float* __restrict__ shift,
                                                float* __restrict__ out0,
                                                float* __restrict__ out1) {
  __shared__ float T[32][33];
  const int p0 = blockIdx.x * 32;
  const int c0 = blockIdx.y * 32;
  const int bb = blockIdx.z;
  const int tx = threadIdx.x;   // 32
  const int ty = threadIdx.y;   // 8
#pragma unroll
  for (int i = 0; i < 4; i++) {
    int cl = ty + 8 * i;
    int c = c0 + cl;
    size_t a = ((size_t)(bb * DMODEL + c) << 10) + p0 + tx;
    float val = fmaxf(fmaf(y2[a], scale[c], shift[c]), 0.0f);
    out1[a] = val;
    T[cl][tx] = val;
  }
  __syncthreads();
#pragma unroll
  for (int i = 0; i < 4; i++) {
    int pl = ty + 8 * i;
    size_t a = ((size_t)((bb << 10) + p0 + pl)) * DMODEL + c0 + tx;
    out0[a] += T[tx][pl];
  }
}

extern "C" void kernel_launch(void* const* d_in, const int* in_sizes, int n_in,
                              void* d_out, int out_size, void* d_ws, size_t ws_size,
                              hipStream_t stream) {
  (void)in_sizes; (void)n_in; (void)out_size; (void)ws_size;
  const float* x    = (const float*)d_in[0];
  const float* y    = (const float*)d_in[1];
  const float* dm   = (const float*)d_in[2];
  const float* wqkv = (const float*)d_in[3];
  const float* w1   = (const float*)d_in[4];
  const float* w2   = (const float*)d_in[5];
  const float* gam  = (const float*)d_in[6];
  const float* bet  = (const float*)d_in[7];
  float* out0 = (float*)d_out;
  float* out1 = out0 + (size_t)B_ * NTOK * DMODEL;
  float* W = (float*)d_ws;
  float* q  = W + WQ0;
  float* kk = W + WK0;
  float* vv = W + WV0;
  float* y1 = W + WY1;
  float* y2 = W + WY2;
  float* sc = W + WSC;
  float* sh = W + WSH;

  k_qkv_gemm<<<dim3(36, 64), 256, 0, stream>>>(x, wqkv, q, kk, vv);
  k_dwconv<<<dim3(B_ * IMGC), 256, 0, stream>>>(y, w1, y1);
  k_conv1x1<<<dim3(16, 12, B_), 256, 0, stream>>>(w2, y1, y2);
  k_bnstats<<<dim3(DMODEL), 256, 0, stream>>>(y2, gam, bet, sc, sh);
  k_attn<<<dim3(48, 32), 256, 0, stream>>>(q, kk, vv, dm, out0);
  k_bnfuse<<<dim3(32, 24, B_), dim3(32, 8), 0, stream>>>(y2, sc, sh, out0, out1);
}

// Round 2
// 369.381 us; speedup vs baseline: 2.8111x; 2.8111x over previous
//
#include <hip/hip_runtime.h>
#include <cstddef>

#define B_     4
#define NTOK   1024
#define DMODEL 768
#define NH     12
#define IMGC   256
#define NPIX   1024

typedef __attribute__((ext_vector_type(8))) short bf16x8;
typedef __attribute__((ext_vector_type(4))) float f32x4;
typedef __attribute__((ext_vector_type(8))) unsigned short u16x8;

static __device__ __forceinline__ unsigned short f2bf(float f) {
  unsigned int u = __float_as_uint(f);
  u += 0x7FFFu + ((u >> 16) & 1u);
  return (unsigned short)(u >> 16);
}

// swizzled LDS byte address: 128B rows, XOR bits 4..6 with row&7
#define SWZ(row, b) (((row) << 7) + ((b) ^ (((row) & 7) << 4)))

// ---------------- K1: QKV GEMM  [4096,768] @ [768,2304] -> bf16 q/k/v [b,h,n,hd]
__global__ __launch_bounds__(256) void k_qkv_gemm(const float* __restrict__ X,
                                                  const float* __restrict__ W,
                                                  unsigned short* __restrict__ q,
                                                  unsigned short* __restrict__ k,
                                                  unsigned short* __restrict__ v) {
  __shared__ __align__(16) float As[64][18];
  __shared__ __align__(16) float Bt[64][18];   // B transposed: [col][kk]
  const int t  = threadIdx.x;
  const int tx = t & 15, ty = t >> 4;
  const int m0 = blockIdx.y * 64;
  const int n0 = blockIdx.x * 64;
  const int lcol = t & 63, lrow4 = (t >> 6) << 2;
  const int ar = t >> 2, ac = (t & 3) << 2;
  float acc[4][4] = {};
  for (int k0 = 0; k0 < 768; k0 += 16) {
    float4 a4 = *(const float4*)&X[(size_t)(m0 + ar) * 768 + k0 + ac];
    *(float2*)&As[ar][ac]     = make_float2(a4.x, a4.y);
    *(float2*)&As[ar][ac + 2] = make_float2(a4.z, a4.w);
#pragma unroll
    for (int rep = 0; rep < 4; rep++) {
      int row = lrow4 + rep;
      Bt[lcol][row] = W[(size_t)(k0 + row) * 2304 + n0 + lcol];
    }
    __syncthreads();
#pragma unroll
    for (int kk = 0; kk < 16; kk += 2) {
      float2 a[4], b[4];
#pragma unroll
      for (int i = 0; i < 4; i++) a[i] = *(const float2*)&As[ty + 16 * i][kk];
#pragma unroll
      for (int j = 0; j < 4; j++) b[j] = *(const float2*)&Bt[tx + 16 * j][kk];
#pragma unroll
      for (int i = 0; i < 4; i++)
#pragma unroll
        for (int j = 0; j < 4; j++) {
          acc[i][j] = fmaf(a[i].x, b[j].x, acc[i][j]);
          acc[i][j] = fmaf(a[i].y, b[j].y, acc[i][j]);
        }
    }
    __syncthreads();
  }
#pragma unroll
  for (int i = 0; i < 4; i++) {
    const int m = m0 + ty + 16 * i;
    const int bb = m >> 10, nn = m & 1023;
#pragma unroll
    for (int j = 0; j < 4; j++) {
      const int ng = n0 + tx + 16 * j;
      const int which = ng / 768;
      const int c = ng - which * 768;
      const int head = c >> 6, dim = c & 63;
      unsigned short* dst = which == 0 ? q : (which == 1 ? k : v);
      dst[((size_t)((bb * NH + head) << 10) + nn) * 64 + dim] = f2bf(acc[i][j]);
    }
  }
}

// ---------------- K2: flash attention, bf16 MFMA. grid(48 bh, 16 qtiles), 256 thr
__global__ __launch_bounds__(256) void k_attn(const unsigned short* __restrict__ qb,
                                              const unsigned short* __restrict__ kb,
                                              const unsigned short* __restrict__ vb,
                                              const float* __restrict__ dm,
                                              float* __restrict__ out0) {
  __shared__ __align__(16) unsigned short QsA[4096];
  __shared__ __align__(16) unsigned short KsA[4096];
  __shared__ __align__(16) unsigned short VtA[4096];   // transposed [d][j]
  __shared__ __align__(16) unsigned short PsA[4096];
  char* qs = (char*)QsA; char* ks = (char*)KsA;
  char* vt = (char*)VtA; char* ps = (char*)PsA;
  const int bh = blockIdx.x;       // b*12+h
  const int qt = blockIdx.y;       // 0..15 (64-row q tiles)
  const int t  = threadIdx.x;
  const int w = t >> 6, l = t & 63, r = l & 15, g = l >> 4;
  const size_t hbase = (size_t)bh << 16;   // 1024*64 elements
  const char* qg = (const char*)(qb + hbase + ((size_t)qt << 12));
  const char* kg = (const char*)(kb + hbase);
  const char* vg = (const char*)(vb + hbase);
  const float* mp = dm + ((size_t)bh << 20) + ((size_t)(qt * 64) << 10);

  // stage Q tile once: 64 rows x 128B, swizzled
#pragma unroll
  for (int i = 0; i < 2; i++) {
    int cid = t + (i << 8);
    int row = cid >> 3, slot = cid & 7;
    uint4 val = *(const uint4*)(qg + row * 128 + slot * 16);
    *(uint4*)(qs + SWZ(row, slot * 16)) = val;
  }

  float m_run[4] = {-INFINITY, -INFINITY, -INFINITY, -INFINITY};
  float l_run[4] = {0.0f, 0.0f, 0.0f, 0.0f};
  f32x4 O[4] = {};

  for (int kt = 0; kt < 16; kt++) {
    __syncthreads();     // prev tile fully consumed (barrier drains all cnts)
    // stage K tile
#pragma unroll
    for (int i = 0; i < 2; i++) {
      int cid = t + (i << 8);
      int row = cid >> 3, slot = cid & 7;
      uint4 val = *(const uint4*)(kg + (size_t)(kt * 64 + row) * 128 + slot * 16);
      *(uint4*)(ks + SWZ(row, slot * 16)) = val;
    }
    // stage V transposed: thread covers row j, dims dh*16..+15
    {
      int j = t & 63, dh = t >> 6;
      const char* vrow = vg + (size_t)(kt * 64 + j) * 128 + dh * 32;
      u16x8 v0 = *(const u16x8*)(vrow);
      u16x8 v1 = *(const u16x8*)(vrow + 16);
#pragma unroll
      for (int e = 0; e < 8; e++) {
        *(unsigned short*)(vt + SWZ(dh * 16 + e, 2 * j))     = v0[e];
        *(unsigned short*)(vt + SWZ(dh * 16 + 8 + e, 2 * j)) = v1[e];
      }
    }
    // issue mask loads early (overlap staging + MFMA latency)
    float md[4][4];
    {
      const float* mr = mp + (size_t)(w * 16 + g * 4) * 1024 + kt * 64 + r;
#pragma unroll
      for (int reg = 0; reg < 4; reg++)
#pragma unroll
        for (int jt = 0; jt < 4; jt++)
          md[reg][jt] = mr[reg * 1024 + jt * 16];
    }
    __syncthreads();     // tiles staged

    // ---- QK^T: wave w computes rows w*16..+15 x 64 cols
    f32x4 s[4] = {};
    bf16x8 aQ[2];
#pragma unroll
    for (int kc = 0; kc < 2; kc++)
      aQ[kc] = *(const bf16x8*)(qs + SWZ(w * 16 + r, kc * 64 + g * 16));
#pragma unroll
    for (int jt = 0; jt < 4; jt++) {
#pragma unroll
      for (int kc = 0; kc < 2; kc++) {
        bf16x8 bK = *(const bf16x8*)(ks + SWZ(jt * 16 + r, kc * 64 + g * 16));
        s[jt] = __builtin_amdgcn_mfma_f32_16x16x32_bf16(aQ[kc], bK, s[jt], 0, 0, 0);
      }
    }
    // scale + dropkey mask  (D layout: row=(g*4+reg), col=jt*16+r)
    float sv[4][4];
#pragma unroll
    for (int jt = 0; jt < 4; jt++)
#pragma unroll
      for (int reg = 0; reg < 4; reg++)
        sv[jt][reg] = s[jt][reg] * 0.125f + (md[reg][jt] < 0.1f ? -1e12f : 0.0f);

    // ---- online softmax, all lanes active (16-lane row groups)
    float alpha[4];
#pragma unroll
    for (int reg = 0; reg < 4; reg++) {
      float mt = fmaxf(fmaxf(sv[0][reg], sv[1][reg]), fmaxf(sv[2][reg], sv[3][reg]));
      mt = fmaxf(mt, __shfl_xor(mt, 1));
      mt = fmaxf(mt, __shfl_xor(mt, 2));
      mt = fmaxf(mt, __shfl_xor(mt, 4));
      mt = fmaxf(mt, __shfl_xor(mt, 8));
      float mn = fmaxf(m_run[reg], mt);
      alpha[reg] = __expf(m_run[reg] - mn);
      m_run[reg] = mn;
    }
#pragma unroll
    for (int reg = 0; reg < 4; reg++) {
      int row = w * 16 + g * 4 + reg;
      float ps_ = 0.0f;
#pragma unroll
      for (int jt = 0; jt < 4; jt++) {
        float p = __expf(sv[jt][reg] - m_run[reg]);
        ps_ += p;
        *(unsigned short*)(ps + SWZ(row, 2 * (jt * 16 + r))) = f2bf(p);
      }
      ps_ += __shfl_xor(ps_, 1);
      ps_ += __shfl_xor(ps_, 2);
      ps_ += __shfl_xor(ps_, 4);
      ps_ += __shfl_xor(ps_, 8);
      l_run[reg] = l_run[reg] * alpha[reg] + ps_;
    }
#pragma unroll
    for (int dt = 0; dt < 4; dt++)
#pragma unroll
      for (int reg = 0; reg < 4; reg++)
        O[dt][reg] *= alpha[reg];
    // P writes are same-wave-read only: drain DS, fence scheduler (rule 18)
    asm volatile("s_waitcnt lgkmcnt(0)" ::: "memory");
    __builtin_amdgcn_sched_barrier(0);
    // ---- PV
#pragma unroll
    for (int kc = 0; kc < 2; kc++) {
      bf16x8 aP = *(const bf16x8*)(ps + SWZ(w * 16 + r, kc * 64 + g * 16));
#pragma unroll
      for (int dt = 0; dt < 4; dt++) {
        bf16x8 bV = *(const bf16x8*)(vt + SWZ(dt * 16 + r, kc * 64 + g * 16));
        O[dt] = __builtin_amdgcn_mfma_f32_16x16x32_bf16(aP, bV, O[dt], 0, 0, 0);
      }
    }
  }
  const int bb = bh / NH, hh = bh % NH;
  float inv[4];
#pragma unroll
  for (int reg = 0; reg < 4; reg++) inv[reg] = 1.0f / l_run[reg];
  float* op = out0 + ((size_t)(bb * 1024 + qt * 64 + w * 16 + g * 4)) * 768 + hh * 64 + r;
#pragma unroll
  for (int reg = 0; reg < 4; reg++)
#pragma unroll
    for (int dt = 0; dt < 4; dt++)
      op[(size_t)reg * 768 + dt * 16] = O[dt][reg] * inv[reg];
}

// ---------------- K3: depthwise 3x3 'SAME'
__global__ __launch_bounds__(256) void k_dwconv(const float* __restrict__ y,
                                                const float* __restrict__ w1,
                                                float* __restrict__ y1) {
  const int bc = blockIdx.x;           // b*256 + c
  const int c = bc & 255;
  const float* yin = y + (size_t)bc * NPIX;
  float* yout = y1 + (size_t)bc * NPIX;
  float w[9];
#pragma unroll
  for (int i = 0; i < 9; i++) w[i] = w1[c * 9 + i];
  const int t = threadIdx.x;
#pragma unroll
  for (int rep = 0; rep < 4; rep++) {
    int px = t + rep * 256;
    int yy = px >> 5, xx = px & 31;
    float acc = 0.0f;
#pragma unroll
    for (int dy = -1; dy <= 1; dy++) {
      int sy = yy + dy;
      if (sy < 0 || sy > 31) continue;
#pragma unroll
      for (int dx = -1; dx <= 1; dx++) {
        int sx = xx + dx;
        if (sx < 0 || sx > 31) continue;
        acc = fmaf(yin[(sy << 5) + sx], w[(dy + 1) * 3 + dx + 1], acc);
      }
    }
    yout[px] = acc;
  }
}

// ---------------- K4: 1x1 conv = per-batch GEMM W2[768,256] @ Y1[256,1024]
__global__ __launch_bounds__(256) void k_conv1x1(const float* __restrict__ W2,
                                                 const float* __restrict__ Y1,
                                                 float* __restrict__ Y2) {
  __shared__ __align__(16) float As[64][18];
  __shared__ __align__(16) float Bt[64][18];
  const int t  = threadIdx.x;
  const int tx = t & 15, ty = t >> 4;
  const int n0 = blockIdx.x * 64;
  const int m0 = blockIdx.y * 64;
  const int bb = blockIdx.z;
  const float* Bb = Y1 + (size_t)bb * IMGC * NPIX;
  const int lcol = t & 63, lrow4 = (t >> 6) << 2;
  const int ar = t >> 2, ac = (t & 3) << 2;
  float acc[4][4] = {};
  for (int k0 = 0; k0 < 256; k0 += 16) {
    float4 a4 = *(const float4*)&W2[(size_t)(m0 + ar) * 256 + k0 + ac];
    *(float2*)&As[ar][ac]     = make_float2(a4.x, a4.y);
    *(float2*)&As[ar][ac + 2] = make_float2(a4.z, a4.w);
#pragma unroll
    for (int rep = 0; rep < 4; rep++) {
      int row = lrow4 + rep;
      Bt[lcol][row] = Bb[(size_t)(k0 + row) * 1024 + n0 + lcol];
    }
    __syncthreads();
#pragma unroll
    for (int kk = 0; kk < 16; kk += 2) {
      float2 a[4], b[4];
#pragma unroll
      for (int i = 0; i < 4; i++) a[i] = *(const float2*)&As[ty + 16 * i][kk];
#pragma unroll
      for (int j = 0; j < 4; j++) b[j] = *(const float2*)&Bt[tx + 16 * j][kk];
#pragma unroll
      for (int i = 0; i < 4; i++)
#pragma unroll
        for (int j = 0; j < 4; j++) {
          acc[i][j] = fmaf(a[i].x, b[j].x, acc[i][j]);
          acc[i][j] = fmaf(a[i].y, b[j].y, acc[i][j]);
        }
    }
    __syncthreads();
  }
#pragma unroll
  for (int i = 0; i < 4; i++) {
    int oc = m0 + ty + 16 * i;
#pragma unroll
    for (int j = 0; j < 4; j++) {
      int p = n0 + tx + 16 * j;
      Y2[((size_t)(bb * DMODEL + oc) << 10) + p] = acc[i][j];
    }
  }
}

// ---------------- K5: BN train stats -> scale/shift per channel
__global__ __launch_bounds__(256) void k_bnstats(const float* __restrict__ y2,
                                                 const float* __restrict__ gamma,
                                                 const float* __restrict__ beta,
                                                 float* __restrict__ scale,
                                                 float* __restrict__ shift) {
  const int c = blockIdx.x;
  const int t = threadIdx.x;
  float s = 0.0f, sq = 0.0f;
  for (int idx = t; idx < 4096; idx += 256) {
    int bb = idx >> 10, p = idx & 1023;
    float val = y2[((size_t)(bb * DMODEL + c) << 10) + p];
    s += val; sq = fmaf(val, val, sq);
  }
#pragma unroll
  for (int off = 32; off > 0; off >>= 1) {
    s += __shfl_down(s, off);
    sq += __shfl_down(sq, off);
  }
  __shared__ float red[8];
  const int wid = t >> 6, lid = t & 63;
  if (lid == 0) { red[wid] = s; red[4 + wid] = sq; }
  __syncthreads();
  if (t == 0) {
    float S = red[0] + red[1] + red[2] + red[3];
    float SQ = red[4] + red[5] + red[6] + red[7];
    float mean = S * (1.0f / 4096.0f);
    float var = SQ * (1.0f / 4096.0f) - mean * mean;
    float rstd = rsqrtf(var + 1e-5f);
    float sc = gamma[c] * rstd;
    scale[c] = sc;
    shift[c] = fmaf(-mean, sc, beta[c]);
  }
}

// ---------------- K6: BN+ReLU -> out1, LDS-transpose add into out0
__global__ __launch_bounds__(256) void k_bnfuse(const float* __restrict__ y2,
                                               const float* __restrict__ scale,
                                               const float* __restrict__ shift,
                                               float* __restrict__ out0,
                                               float* __restrict__ out1) {
  __shared__ float T[32][33];
  const int p0 = blockIdx.x * 32;
  const int c0 = blockIdx.y * 32;
  const int bb = blockIdx.z;
  const int tx = threadIdx.x;   // 32
  const int ty = threadIdx.y;   // 8
#pragma unroll
  for (int i = 0; i < 4; i++) {
    int cl = ty + 8 * i;
    int c = c0 + cl;
    size_t a = ((size_t)(bb * DMODEL + c) << 10) + p0 + tx;
    float val = fmaxf(fmaf(y2[a], scale[c], shift[c]), 0.0f);
    out1[a] = val;
    T[cl][tx] = val;
  }
  __syncthreads();
#pragma unroll
  for (int i = 0; i < 4; i++) {
    int pl = ty + 8 * i;
    size_t a = ((size_t)((bb << 10) + p0 + pl)) * DMODEL + c0 + tx;
    out0[a] += T[tx][pl];
  }
}

extern "C" void kernel_launch(void* const* d_in, const int* in_sizes, int n_in,
                              void* d_out, int out_size, void* d_ws, size_t ws_size,
                              hipStream_t stream) {
  (void)in_sizes; (void)n_in; (void)out_size; (void)ws_size;
  const float* x    = (const float*)d_in[0];
  const float* y    = (const float*)d_in[1];
  const float* dm   = (const float*)d_in[2];
  const float* wqkv = (const float*)d_in[3];
  const float* w1   = (const float*)d_in[4];
  const float* w2   = (const float*)d_in[5];
  const float* gam  = (const float*)d_in[6];
  const float* bet  = (const float*)d_in[7];
  float* out0 = (float*)d_out;
  float* out1 = out0 + (size_t)B_ * NTOK * DMODEL;

  unsigned short* qb = (unsigned short*)d_ws;         // 3145728 bf16 each
  unsigned short* kb = qb + 3145728;
  unsigned short* vb = kb + 3145728;
  float* y1 = (float*)((char*)d_ws + (size_t)3 * 3145728 * 2);  // 18874368 B
  float* y2 = y1 + (size_t)IMGC * NPIX * B_;          // +1048576 floats
  float* sc = y2 + (size_t)B_ * DMODEL * NPIX;        // +3145728 floats
  float* sh = sc + DMODEL;

  k_qkv_gemm<<<dim3(36, 64), 256, 0, stream>>>(x, wqkv, qb, kb, vb);
  k_dwconv<<<dim3(B_ * IMGC), 256, 0, stream>>>(y, w1, y1);
  k_conv1x1<<<dim3(16, 12, B_), 256, 0, stream>>>(w2, y1, y2);
  k_bnstats<<<dim3(DMODEL), 256, 0, stream>>>(y2, gam, bet, sc, sh);
  k_attn<<<dim3(48, 16), 256, 0, stream>>>(qb, kb, vb, dm, out0);
  k_bnfuse<<<dim3(32, 24, B_), dim3(32, 8), 0, stream>>>(y2, sc, sh, out0, out1);
}

// Round 3
// 154.406 us; speedup vs baseline: 6.7249x; 2.3923x over previous
//
#include <hip/hip_runtime.h>
#include <cstddef>

#define B_     4
#define NTOK   1024
#define DMODEL 768
#define NH     12
#define IMGC   256
#define NPIX   1024

typedef __attribute__((ext_vector_type(8))) short bf16x8;
typedef __attribute__((ext_vector_type(4))) float f32x4;
typedef __attribute__((ext_vector_type(8))) unsigned short u16x8;

static __device__ __forceinline__ unsigned short f2bf(float f) {
  unsigned int u = __float_as_uint(f);
  u += 0x7FFFu + ((u >> 16) & 1u);
  return (unsigned short)(u >> 16);
}

// swizzled LDS byte address: 128B rows, XOR bits 4..6 with row&7
#define SWZ(row, b) (((row) << 7) + ((b) ^ (((row) & 7) << 4)))

#define GLOAD16(g, l) __builtin_amdgcn_global_load_lds(                      \
    (const __attribute__((address_space(1))) void*)(g),                      \
    (__attribute__((address_space(3))) void*)(l), 16, 0, 0)

// ---------------- K0a: X f32 -> bf16
__global__ __launch_bounds__(256) void k_cvt_x(const float* __restrict__ X,
                                               unsigned short* __restrict__ Xb) {
  const size_t i8 = (size_t)blockIdx.x * 256 + threadIdx.x;
  const float4 a = *(const float4*)(X + i8 * 8);
  const float4 b = *(const float4*)(X + i8 * 8 + 4);
  u16x8 o;
  o[0] = f2bf(a.x); o[1] = f2bf(a.y); o[2] = f2bf(a.z); o[3] = f2bf(a.w);
  o[4] = f2bf(b.x); o[5] = f2bf(b.y); o[6] = f2bf(b.z); o[7] = f2bf(b.w);
  *(u16x8*)(Xb + i8 * 8) = o;
}

// ---------------- K0b: W [768][2304] f32 -> Wt [2304][768] bf16
__global__ __launch_bounds__(256) void k_cvt_wt(const float* __restrict__ W,
                                                unsigned short* __restrict__ Wt) {
  __shared__ unsigned short T[32][33];
  const int tx = threadIdx.x;            // 32
  const int ty = threadIdx.y;            // 8
  const int n0 = blockIdx.x * 32;        // 72 blocks
  const int k0 = blockIdx.y * 32;        // 24 blocks
#pragma unroll
  for (int i = 0; i < 4; i++) {
    int kl = ty + i * 8;
    T[tx][kl] = f2bf(W[(size_t)(k0 + kl) * 2304 + n0 + tx]);
  }
  __syncthreads();
#pragma unroll
  for (int i = 0; i < 4; i++) {
    int nl = ty + i * 8;
    Wt[(size_t)(n0 + nl) * 768 + k0 + tx] = T[nl][tx];
  }
}

// ---------------- K1: QKV GEMM bf16 MFMA. [4096,768]x[768,2304]
// tile 128x128, BK=64, 4 waves (2x2 of 64x64), grid(18,32)
__global__ __launch_bounds__(256) void k_qkv_gemm(const unsigned short* __restrict__ Xb,
                                                  const unsigned short* __restrict__ Wt,
                                                  unsigned short* __restrict__ q,
                                                  unsigned short* __restrict__ k,
                                                  unsigned short* __restrict__ v) {
  __shared__ __align__(16) char AsB[16384];
  __shared__ __align__(16) char BsB[16384];
  const int t = threadIdx.x;
  const int w = t >> 6, l = t & 63;
  const int r = l & 15, g = l >> 4;
  const int wr = w >> 1, wc = w & 1;
  const int m0 = blockIdx.y * 128;
  const int n0 = blockIdx.x * 128;
  const int rsel  = l >> 3;                 // row within 8-row chunk
  const int slotp = (l & 7) ^ (rsel & 7);   // pre-swizzled 16B slot
  f32x4 acc[4][4] = {};

  for (int step = 0; step < 12; ++step) {
    const int k0 = step * 64;
#pragma unroll
    for (int i = 0; i < 4; i++) {
      const int chunk = (i << 2) + w;             // wave-uniform
      const int row = (chunk << 3) + rsel;        // 0..127
      GLOAD16(Xb + (size_t)(m0 + row) * 768 + k0 + (slotp << 3),
              AsB + (chunk << 10) + (l << 4));
      GLOAD16(Wt + (size_t)(n0 + row) * 768 + k0 + (slotp << 3),
              BsB + (chunk << 10) + (l << 4));
    }
    __syncthreads();
#pragma unroll
    for (int kk = 0; kk < 2; kk++) {
      bf16x8 a[4], b[4];
#pragma unroll
      for (int m = 0; m < 4; m++) {
        const int row = wr * 64 + m * 16 + r;
        a[m] = *(const bf16x8*)(AsB + SWZ(row, kk * 64 + (g << 4)));
      }
#pragma unroll
      for (int n = 0; n < 4; n++) {
        const int row = wc * 64 + n * 16 + r;
        b[n] = *(const bf16x8*)(BsB + SWZ(row, kk * 64 + (g << 4)));
      }
#pragma unroll
      for (int m = 0; m < 4; m++)
#pragma unroll
        for (int n = 0; n < 4; n++)
          acc[m][n] = __builtin_amdgcn_mfma_f32_16x16x32_bf16(a[m], b[n], acc[m][n], 0, 0, 0);
    }
    __syncthreads();
  }

  // epilogue: C row=(g*4+reg) col=r per 16x16 frag
  const int which = blockIdx.x / 6;                 // 768 = 6*128 -> no straddle
  const int cbase = (blockIdx.x - which * 6) * 128 + wc * 64;
  unsigned short* dst = which == 0 ? q : (which == 1 ? k : v);
#pragma unroll
  for (int m = 0; m < 4; m++) {
    const int grow = m0 + wr * 64 + m * 16 + g * 4;
#pragma unroll
    for (int n = 0; n < 4; n++) {
      const int c = cbase + n * 16 + r;
      const int head = c >> 6, dim = c & 63;
#pragma unroll
      for (int reg = 0; reg < 4; reg++) {
        const int row = grow + reg;
        const int bb = row >> 10, tok = row & 1023;
        dst[((size_t)(((bb * NH + head) << 10) + tok) << 6) + dim] = f2bf(acc[m][n][reg]);
      }
    }
  }
}

// ---------------- K2: flash attention, bf16 MFMA. grid(48 bh, 16 qtiles), 256 thr
__global__ __launch_bounds__(256) void k_attn(const unsigned short* __restrict__ qb,
                                              const unsigned short* __restrict__ kb,
                                              const unsigned short* __restrict__ vb,
                                              const float* __restrict__ dm,
                                              float* __restrict__ out0) {
  __shared__ __align__(16) unsigned short QsA[4096];
  __shared__ __align__(16) unsigned short KsA[4096];
  __shared__ __align__(16) unsigned short VtA[4096];   // transposed [d][j]
  __shared__ __align__(16) unsigned short PsA[4096];
  char* qs = (char*)QsA; char* ks = (char*)KsA;
  char* vt = (char*)VtA; char* ps = (char*)PsA;
  const int bh = blockIdx.x;       // b*12+h
  const int qt = blockIdx.y;       // 0..15 (64-row q tiles)
  const int t  = threadIdx.x;
  const int w = t >> 6, l = t & 63, r = l & 15, g = l >> 4;
  const size_t hbase = (size_t)bh << 16;   // 1024*64 elements
  const char* qg = (const char*)(qb + hbase + ((size_t)qt << 12));
  const char* kg = (const char*)(kb + hbase);
  const char* vg = (const char*)(vb + hbase);
  const float* mp = dm + ((size_t)bh << 20) + ((size_t)(qt * 64) << 10);

  // stage Q tile once: 64 rows x 128B, swizzled
#pragma unroll
  for (int i = 0; i < 2; i++) {
    int cid = t + (i << 8);
    int row = cid >> 3, slot = cid & 7;
    uint4 val = *(const uint4*)(qg + row * 128 + slot * 16);
    *(uint4*)(qs + SWZ(row, slot * 16)) = val;
  }

  float m_run[4] = {-INFINITY, -INFINITY, -INFINITY, -INFINITY};
  float l_run[4] = {0.0f, 0.0f, 0.0f, 0.0f};
  f32x4 O[4] = {};

  for (int kt = 0; kt < 16; kt++) {
    __syncthreads();     // prev tile fully consumed (barrier drains all cnts)
    // stage K tile
#pragma unroll
    for (int i = 0; i < 2; i++) {
      int cid = t + (i << 8);
      int row = cid >> 3, slot = cid & 7;
      uint4 val = *(const uint4*)(kg + (size_t)(kt * 64 + row) * 128 + slot * 16);
      *(uint4*)(ks + SWZ(row, slot * 16)) = val;
    }
    // stage V transposed: thread covers row j, dims dh*16..+15
    {
      int j = t & 63, dh = t >> 6;
      const char* vrow = vg + (size_t)(kt * 64 + j) * 128 + dh * 32;
      u16x8 v0 = *(const u16x8*)(vrow);
      u16x8 v1 = *(const u16x8*)(vrow + 16);
#pragma unroll
      for (int e = 0; e < 8; e++) {
        *(unsigned short*)(vt + SWZ(dh * 16 + e, 2 * j))     = v0[e];
        *(unsigned short*)(vt + SWZ(dh * 16 + 8 + e, 2 * j)) = v1[e];
      }
    }
    // issue mask loads early (overlap staging + MFMA latency)
    float md[4][4];
    {
      const float* mr = mp + (size_t)(w * 16 + g * 4) * 1024 + kt * 64 + r;
#pragma unroll
      for (int reg = 0; reg < 4; reg++)
#pragma unroll
        for (int jt = 0; jt < 4; jt++)
          md[reg][jt] = mr[reg * 1024 + jt * 16];
    }
    __syncthreads();     // tiles staged

    // ---- QK^T: wave w computes rows w*16..+15 x 64 cols
    f32x4 s[4] = {};
    bf16x8 aQ[2];
#pragma unroll
    for (int kc = 0; kc < 2; kc++)
      aQ[kc] = *(const bf16x8*)(qs + SWZ(w * 16 + r, kc * 64 + g * 16));
#pragma unroll
    for (int jt = 0; jt < 4; jt++) {
#pragma unroll
      for (int kc = 0; kc < 2; kc++) {
        bf16x8 bK = *(const bf16x8*)(ks + SWZ(jt * 16 + r, kc * 64 + g * 16));
        s[jt] = __builtin_amdgcn_mfma_f32_16x16x32_bf16(aQ[kc], bK, s[jt], 0, 0, 0);
      }
    }
    // scale + dropkey mask  (D layout: row=(g*4+reg), col=jt*16+r)
    float sv[4][4];
#pragma unroll
    for (int jt = 0; jt < 4; jt++)
#pragma unroll
      for (int reg = 0; reg < 4; reg++)
        sv[jt][reg] = s[jt][reg] * 0.125f + (md[reg][jt] < 0.1f ? -1e12f : 0.0f);

    // ---- online softmax, all lanes active (16-lane row groups)
    float alpha[4];
#pragma unroll
    for (int reg = 0; reg < 4; reg++) {
      float mt = fmaxf(fmaxf(sv[0][reg], sv[1][reg]), fmaxf(sv[2][reg], sv[3][reg]));
      mt = fmaxf(mt, __shfl_xor(mt, 1));
      mt = fmaxf(mt, __shfl_xor(mt, 2));
      mt = fmaxf(mt, __shfl_xor(mt, 4));
      mt = fmaxf(mt, __shfl_xor(mt, 8));
      float mn = fmaxf(m_run[reg], mt);
      alpha[reg] = __expf(m_run[reg] - mn);
      m_run[reg] = mn;
    }
#pragma unroll
    for (int reg = 0; reg < 4; reg++) {
      int row = w * 16 + g * 4 + reg;
      float ps_ = 0.0f;
#pragma unroll
      for (int jt = 0; jt < 4; jt++) {
        float p = __expf(sv[jt][reg] - m_run[reg]);
        ps_ += p;
        *(unsigned short*)(ps + SWZ(row, 2 * (jt * 16 + r))) = f2bf(p);
      }
      ps_ += __shfl_xor(ps_, 1);
      ps_ += __shfl_xor(ps_, 2);
      ps_ += __shfl_xor(ps_, 4);
      ps_ += __shfl_xor(ps_, 8);
      l_run[reg] = l_run[reg] * alpha[reg] + ps_;
    }
#pragma unroll
    for (int dt = 0; dt < 4; dt++)
#pragma unroll
      for (int reg = 0; reg < 4; reg++)
        O[dt][reg] *= alpha[reg];
    // P writes are same-wave-read only: drain DS, fence scheduler (rule 18)
    asm volatile("s_waitcnt lgkmcnt(0)" ::: "memory");
    __builtin_amdgcn_sched_barrier(0);
    // ---- PV
#pragma unroll
    for (int kc = 0; kc < 2; kc++) {
      bf16x8 aP = *(const bf16x8*)(ps + SWZ(w * 16 + r, kc * 64 + g * 16));
#pragma unroll
      for (int dt = 0; dt < 4; dt++) {
        bf16x8 bV = *(const bf16x8*)(vt + SWZ(dt * 16 + r, kc * 64 + g * 16));
        O[dt] = __builtin_amdgcn_mfma_f32_16x16x32_bf16(aP, bV, O[dt], 0, 0, 0);
      }
    }
  }
  const int bb = bh / NH, hh = bh % NH;
  float inv[4];
#pragma unroll
  for (int reg = 0; reg < 4; reg++) inv[reg] = 1.0f / l_run[reg];
  float* op = out0 + ((size_t)(bb * 1024 + qt * 64 + w * 16 + g * 4)) * 768 + hh * 64 + r;
#pragma unroll
  for (int reg = 0; reg < 4; reg++)
#pragma unroll
    for (int dt = 0; dt < 4; dt++)
      op[(size_t)reg * 768 + dt * 16] = O[dt][reg] * inv[reg];
}

// ---------------- K3: depthwise 3x3 'SAME'
__global__ __launch_bounds__(256) void k_dwconv(const float* __restrict__ y,
                                                const float* __restrict__ w1,
                                                float* __restrict__ y1) {
  const int bc = blockIdx.x;           // b*256 + c
  const int c = bc & 255;
  const float* yin = y + (size_t)bc * NPIX;
  float* yout = y1 + (size_t)bc * NPIX;
  float w[9];
#pragma unroll
  for (int i = 0; i < 9; i++) w[i] = w1[c * 9 + i];
  const int t = threadIdx.x;
#pragma unroll
  for (int rep = 0; rep < 4; rep++) {
    int px = t + rep * 256;
    int yy = px >> 5, xx = px & 31;
    float acc = 0.0f;
#pragma unroll
    for (int dy = -1; dy <= 1; dy++) {
      int sy = yy + dy;
      if (sy < 0 || sy > 31) continue;
#pragma unroll
      for (int dx = -1; dx <= 1; dx++) {
        int sx = xx + dx;
        if (sx < 0 || sx > 31) continue;
        acc = fmaf(yin[(sy << 5) + sx], w[(dy + 1) * 3 + dx + 1], acc);
      }
    }
    yout[px] = acc;
  }
}

// ---------------- K4: 1x1 conv = per-batch GEMM W2[768,256] @ Y1[256,1024]
__global__ __launch_bounds__(256) void k_conv1x1(const float* __restrict__ W2,
                                                 const float* __restrict__ Y1,
                                                 float* __restrict__ Y2) {
  __shared__ __align__(16) float As[64][18];
  __shared__ __align__(16) float Bt[64][18];
  const int t  = threadIdx.x;
  const int tx = t & 15, ty = t >> 4;
  const int n0 = blockIdx.x * 64;
  const int m0 = blockIdx.y * 64;
  const int bb = blockIdx.z;
  const float* Bb = Y1 + (size_t)bb * IMGC * NPIX;
  const int lcol = t & 63, lrow4 = (t >> 6) << 2;
  const int ar = t >> 2, ac = (t & 3) << 2;
  float acc[4][4] = {};
  for (int k0 = 0; k0 < 256; k0 += 16) {
    float4 a4 = *(const float4*)&W2[(size_t)(m0 + ar) * 256 + k0 + ac];
    *(float2*)&As[ar][ac]     = make_float2(a4.x, a4.y);
    *(float2*)&As[ar][ac + 2] = make_float2(a4.z, a4.w);
#pragma unroll
    for (int rep = 0; rep < 4; rep++) {
      int row = lrow4 + rep;
      Bt[lcol][row] = Bb[(size_t)(k0 + row) * 1024 + n0 + lcol];
    }
    __syncthreads();
#pragma unroll
    for (int kk = 0; kk < 16; kk += 2) {
      float2 a[4], b[4];
#pragma unroll
      for (int i = 0; i < 4; i++) a[i] = *(const float2*)&As[ty + 16 * i][kk];
#pragma unroll
      for (int j = 0; j < 4; j++) b[j] = *(const float2*)&Bt[tx + 16 * j][kk];
#pragma unroll
      for (int i = 0; i < 4; i++)
#pragma unroll
        for (int j = 0; j < 4; j++) {
          acc[i][j] = fmaf(a[i].x, b[j].x, acc[i][j]);
          acc[i][j] = fmaf(a[i].y, b[j].y, acc[i][j]);
        }
    }
    __syncthreads();
  }
#pragma unroll
  for (int i = 0; i < 4; i++) {
    int oc = m0 + ty + 16 * i;
#pragma unroll
    for (int j = 0; j < 4; j++) {
      int p = n0 + tx + 16 * j;
      Y2[((size_t)(bb * DMODEL + oc) << 10) + p] = acc[i][j];
    }
  }
}

// ---------------- K5: BN train stats -> scale/shift per channel
__global__ __launch_bounds__(256) void k_bnstats(const float* __restrict__ y2,
                                                 const float* __restrict__ gamma,
                                                 const float* __restrict__ beta,
                                                 float* __restrict__ scale,
                                                 float* __restrict__ shift) {
  const int c = blockIdx.x;
  const int t = threadIdx.x;
  float s = 0.0f, sq = 0.0f;
  for (int idx = t; idx < 4096; idx += 256) {
    int bb = idx >> 10, p = idx & 1023;
    float val = y2[((size_t)(bb * DMODEL + c) << 10) + p];
    s += val; sq = fmaf(val, val, sq);
  }
#pragma unroll
  for (int off = 32; off > 0; off >>= 1) {
    s += __shfl_down(s, off);
    sq += __shfl_down(sq, off);
  }
  __shared__ float red[8];
  const int wid = t >> 6, lid = t & 63;
  if (lid == 0) { red[wid] = s; red[4 + wid] = sq; }
  __syncthreads();
  if (t == 0) {
    float S = red[0] + red[1] + red[2] + red[3];
    float SQ = red[4] + red[5] + red[6] + red[7];
    float mean = S * (1.0f / 4096.0f);
    float var = SQ * (1.0f / 4096.0f) - mean * mean;
    float rstd = rsqrtf(var + 1e-5f);
    float sc = gamma[c] * rstd;
    scale[c] = sc;
    shift[c] = fmaf(-mean, sc, beta[c]);
  }
}

// ---------------- K6: BN+ReLU -> out1, LDS-transpose add into out0
__global__ __launch_bounds__(256) void k_bnfuse(const float* __restrict__ y2,
                                               const float* __restrict__ scale,
                                               const float* __restrict__ shift,
                                               float* __restrict__ out0,
                                               float* __restrict__ out1) {
  __shared__ float T[32][33];
  const int p0 = blockIdx.x * 32;
  const int c0 = blockIdx.y * 32;
  const int bb = blockIdx.z;
  const int tx = threadIdx.x;   // 32
  const int ty = threadIdx.y;   // 8
#pragma unroll
  for (int i = 0; i < 4; i++) {
    int cl = ty + 8 * i;
    int c = c0 + cl;
    size_t a = ((size_t)(bb * DMODEL + c) << 10) + p0 + tx;
    float val = fmaxf(fmaf(y2[a], scale[c], shift[c]), 0.0f);
    out1[a] = val;
    T[cl][tx] = val;
  }
  __syncthreads();
#pragma unroll
  for (int i = 0; i < 4; i++) {
    int pl = ty + 8 * i;
    size_t a = ((size_t)((bb << 10) + p0 + pl)) * DMODEL + c0 + tx;
    out0[a] += T[tx][pl];
  }
}

extern "C" void kernel_launch(void* const* d_in, const int* in_sizes, int n_in,
                              void* d_out, int out_size, void* d_ws, size_t ws_size,
                              hipStream_t stream) {
  (void)in_sizes; (void)n_in; (void)out_size; (void)ws_size;
  const float* x    = (const float*)d_in[0];
  const float* y    = (const float*)d_in[1];
  const float* dm   = (const float*)d_in[2];
  const float* wqkv = (const float*)d_in[3];
  const float* w1   = (const float*)d_in[4];
  const float* w2   = (const float*)d_in[5];
  const float* gam  = (const float*)d_in[6];
  const float* bet  = (const float*)d_in[7];
  float* out0 = (float*)d_out;
  float* out1 = out0 + (size_t)B_ * NTOK * DMODEL;

  char* wsb = (char*)d_ws;
  unsigned short* Xb  = (unsigned short*)wsb;                 // 6,291,456 B
  unsigned short* Wtb = (unsigned short*)(wsb + 6291456);     // 3,538,944 B
  unsigned short* qb  = (unsigned short*)(wsb + 9830400);     // 6,291,456 B
  unsigned short* kb  = (unsigned short*)(wsb + 16121856);
  unsigned short* vb  = (unsigned short*)(wsb + 22413312);
  float* y1 = (float*)(wsb + 28704768);                       // 4,194,304 B
  float* y2 = (float*)(wsb + 32899072);                       // 12,582,912 B
  float* sc = (float*)(wsb + 45481984);
  float* sh = (float*)(wsb + 45485056);

  k_cvt_x<<<dim3(1536), 256, 0, stream>>>(x, Xb);
  k_cvt_wt<<<dim3(72, 24), dim3(32, 8), 0, stream>>>(wqkv, Wtb);
  k_qkv_gemm<<<dim3(18, 32), 256, 0, stream>>>(Xb, Wtb, qb, kb, vb);
  k_dwconv<<<dim3(B_ * IMGC), 256, 0, stream>>>(y, w1, y1);
  k_conv1x1<<<dim3(16, 12, B_), 256, 0, stream>>>(w2, y1, y2);
  k_bnstats<<<dim3(DMODEL), 256, 0, stream>>>(y2, gam, bet, sc, sh);
  k_attn<<<dim3(48, 16), 256, 0, stream>>>(qb, kb, vb, dm, out0);
  k_bnfuse<<<dim3(32, 24, B_), dim3(32, 8), 0, stream>>>(y2, sc, sh, out0, out1);
}

// Round 4
// 128.892 us; speedup vs baseline: 8.0560x; 1.1979x over previous
//
#include <hip/hip_runtime.h>
#include <cstddef>

#define B_     4
#define NTOK   1024
#define DMODEL 768
#define NH     12
#define IMGC   256
#define NPIX   1024

typedef __attribute__((ext_vector_type(8))) short bf16x8;
typedef __attribute__((ext_vector_type(4))) float f32x4;
typedef __attribute__((ext_vector_type(8))) unsigned short u16x8;

static __device__ __forceinline__ unsigned short f2bf(float f) {
  unsigned int u = __float_as_uint(f);
  u += 0x7FFFu + ((u >> 16) & 1u);
  return (unsigned short)(u >> 16);
}

// swizzled LDS byte address: 128B rows, XOR bits 4..6 with row&7
#define SWZ(row, b) (((row) << 7) + ((b) ^ (((row) & 7) << 4)))

#define GLOAD16(g, l) __builtin_amdgcn_global_load_lds(                      \
    (const __attribute__((address_space(1))) void*)(g),                      \
    (__attribute__((address_space(3))) void*)(l), 16, 0, 0)

// ---------------- K0: merged converts + BN-accumulator zeroing
// blocks [0,1536): X->Xb ; [1536,3264): Wqkv^T->Wtb ; [3264,3360): W2->W2b ;
// block 3360: zero bn accumulators
__global__ __launch_bounds__(256) void k_cvt(const float* __restrict__ X,
                                             const float* __restrict__ Wqkv,
                                             const float* __restrict__ W2,
                                             unsigned short* __restrict__ Xb,
                                             unsigned short* __restrict__ Wtb,
                                             unsigned short* __restrict__ W2b,
                                             float* __restrict__ bnacc) {
  __shared__ unsigned short T[32][33];
  const int bid = blockIdx.x;
  const int t = threadIdx.x;
  if (bid < 1536) {
    const size_t i8 = (size_t)bid * 256 + t;
    const float4 a = *(const float4*)(X + i8 * 8);
    const float4 b = *(const float4*)(X + i8 * 8 + 4);
    u16x8 o;
    o[0] = f2bf(a.x); o[1] = f2bf(a.y); o[2] = f2bf(a.z); o[3] = f2bf(a.w);
    o[4] = f2bf(b.x); o[5] = f2bf(b.y); o[6] = f2bf(b.z); o[7] = f2bf(b.w);
    *(u16x8*)(Xb + i8 * 8) = o;
  } else if (bid < 3264) {
    const int b2 = bid - 1536;
    const int n0 = (b2 % 72) * 32, k0 = (b2 / 72) * 32;
    const int tx = t & 31, ty = t >> 5;
#pragma unroll
    for (int i = 0; i < 4; i++) {
      int kl = ty + i * 8;
      T[tx][kl] = f2bf(Wqkv[(size_t)(k0 + kl) * 2304 + n0 + tx]);
    }
    __syncthreads();
#pragma unroll
    for (int i = 0; i < 4; i++) {
      int nl = ty + i * 8;
      Wtb[(size_t)(n0 + nl) * 768 + k0 + tx] = T[nl][tx];
    }
  } else if (bid < 3360) {
    const size_t i8 = (size_t)(bid - 3264) * 256 + t;
    const float4 a = *(const float4*)(W2 + i8 * 8);
    const float4 b = *(const float4*)(W2 + i8 * 8 + 4);
    u16x8 o;
    o[0] = f2bf(a.x); o[1] = f2bf(a.y); o[2] = f2bf(a.z); o[3] = f2bf(a.w);
    o[4] = f2bf(b.x); o[5] = f2bf(b.y); o[6] = f2bf(b.z); o[7] = f2bf(b.w);
    *(u16x8*)(W2b + i8 * 8) = o;
  } else {
    for (int i = t; i < 1536; i += 256) bnacc[i] = 0.0f;
  }
}

// ---------------- K1: QKV GEMM bf16 MFMA. [4096,768]x[768,2304]
__global__ __launch_bounds__(256) void k_qkv_gemm(const unsigned short* __restrict__ Xb,
                                                  const unsigned short* __restrict__ Wt,
                                                  unsigned short* __restrict__ q,
                                                  unsigned short* __restrict__ k,
                                                  unsigned short* __restrict__ v) {
  __shared__ __align__(16) char AsB[16384];
  __shared__ __align__(16) char BsB[16384];
  const int t = threadIdx.x;
  const int w = t >> 6, l = t & 63;
  const int r = l & 15, g = l >> 4;
  const int wr = w >> 1, wc = w & 1;
  const int m0 = blockIdx.y * 128;
  const int n0 = blockIdx.x * 128;
  const int rsel  = l >> 3;
  const int slotp = (l & 7) ^ (rsel & 7);
  f32x4 acc[4][4] = {};

  for (int step = 0; step < 12; ++step) {
    const int k0 = step * 64;
#pragma unroll
    for (int i = 0; i < 4; i++) {
      const int chunk = (i << 2) + w;
      const int row = (chunk << 3) + rsel;
      GLOAD16(Xb + (size_t)(m0 + row) * 768 + k0 + (slotp << 3),
              AsB + (chunk << 10) + (l << 4));
      GLOAD16(Wt + (size_t)(n0 + row) * 768 + k0 + (slotp << 3),
              BsB + (chunk << 10) + (l << 4));
    }
    __syncthreads();
#pragma unroll
    for (int kk = 0; kk < 2; kk++) {
      bf16x8 a[4], b[4];
#pragma unroll
      for (int m = 0; m < 4; m++) {
        const int row = wr * 64 + m * 16 + r;
        a[m] = *(const bf16x8*)(AsB + SWZ(row, kk * 64 + (g << 4)));
      }
#pragma unroll
      for (int n = 0; n < 4; n++) {
        const int row = wc * 64 + n * 16 + r;
        b[n] = *(const bf16x8*)(BsB + SWZ(row, kk * 64 + (g << 4)));
      }
#pragma unroll
      for (int m = 0; m < 4; m++)
#pragma unroll
        for (int n = 0; n < 4; n++)
          acc[m][n] = __builtin_amdgcn_mfma_f32_16x16x32_bf16(a[m], b[n], acc[m][n], 0, 0, 0);
    }
    __syncthreads();
  }

  const int which = blockIdx.x / 6;
  const int cbase = (blockIdx.x - which * 6) * 128 + wc * 64;
  unsigned short* dst = which == 0 ? q : (which == 1 ? k : v);
#pragma unroll
  for (int m = 0; m < 4; m++) {
    const int grow = m0 + wr * 64 + m * 16 + g * 4;
#pragma unroll
    for (int n = 0; n < 4; n++) {
      const int c = cbase + n * 16 + r;
      const int head = c >> 6, dim = c & 63;
#pragma unroll
      for (int reg = 0; reg < 4; reg++) {
        const int row = grow + reg;
        const int bb = row >> 10, tok = row & 1023;
        dst[((size_t)(((bb * NH + head) << 10) + tok) << 6) + dim] = f2bf(acc[m][n][reg]);
      }
    }
  }
}

// ---------------- K2: flash attention, bf16 MFMA. grid(48 bh, 16 qtiles), 256 thr
__global__ __launch_bounds__(256) void k_attn(const unsigned short* __restrict__ qb,
                                              const unsigned short* __restrict__ kb,
                                              const unsigned short* __restrict__ vb,
                                              const float* __restrict__ dm,
                                              float* __restrict__ out0) {
  __shared__ __align__(16) unsigned short QsA[4096];
  __shared__ __align__(16) unsigned short KsA[4096];
  __shared__ __align__(16) unsigned short VtA[4096];
  __shared__ __align__(16) unsigned short PsA[4096];
  char* qs = (char*)QsA; char* ks = (char*)KsA;
  char* vt = (char*)VtA; char* ps = (char*)PsA;
  const int bh = blockIdx.x;
  const int qt = blockIdx.y;
  const int t  = threadIdx.x;
  const int w = t >> 6, l = t & 63, r = l & 15, g = l >> 4;
  const size_t hbase = (size_t)bh << 16;
  const char* qg = (const char*)(qb + hbase + ((size_t)qt << 12));
  const char* kg = (const char*)(kb + hbase);
  const char* vg = (const char*)(vb + hbase);
  const float* mp = dm + ((size_t)bh << 20) + ((size_t)(qt * 64) << 10);

#pragma unroll
  for (int i = 0; i < 2; i++) {
    int cid = t + (i << 8);
    int row = cid >> 3, slot = cid & 7;
    uint4 val = *(const uint4*)(qg + row * 128 + slot * 16);
    *(uint4*)(qs + SWZ(row, slot * 16)) = val;
  }

  float m_run[4] = {-INFINITY, -INFINITY, -INFINITY, -INFINITY};
  float l_run[4] = {0.0f, 0.0f, 0.0f, 0.0f};
  f32x4 O[4] = {};

  for (int kt = 0; kt < 16; kt++) {
    __syncthreads();
#pragma unroll
    for (int i = 0; i < 2; i++) {
      int cid = t + (i << 8);
      int row = cid >> 3, slot = cid & 7;
      uint4 val = *(const uint4*)(kg + (size_t)(kt * 64 + row) * 128 + slot * 16);
      *(uint4*)(ks + SWZ(row, slot * 16)) = val;
    }
    {
      int j = t & 63, dh = t >> 6;
      const char* vrow = vg + (size_t)(kt * 64 + j) * 128 + dh * 32;
      u16x8 v0 = *(const u16x8*)(vrow);
      u16x8 v1 = *(const u16x8*)(vrow + 16);
#pragma unroll
      for (int e = 0; e < 8; e++) {
        *(unsigned short*)(vt + SWZ(dh * 16 + e, 2 * j))     = v0[e];
        *(unsigned short*)(vt + SWZ(dh * 16 + 8 + e, 2 * j)) = v1[e];
      }
    }
    float md[4][4];
    {
      const float* mr = mp + (size_t)(w * 16 + g * 4) * 1024 + kt * 64 + r;
#pragma unroll
      for (int reg = 0; reg < 4; reg++)
#pragma unroll
        for (int jt = 0; jt < 4; jt++)
          md[reg][jt] = mr[reg * 1024 + jt * 16];
    }
    __syncthreads();

    f32x4 s[4] = {};
    bf16x8 aQ[2];
#pragma unroll
    for (int kc = 0; kc < 2; kc++)
      aQ[kc] = *(const bf16x8*)(qs + SWZ(w * 16 + r, kc * 64 + g * 16));
#pragma unroll
    for (int jt = 0; jt < 4; jt++) {
#pragma unroll
      for (int kc = 0; kc < 2; kc++) {
        bf16x8 bK = *(const bf16x8*)(ks + SWZ(jt * 16 + r, kc * 64 + g * 16));
        s[jt] = __builtin_amdgcn_mfma_f32_16x16x32_bf16(aQ[kc], bK, s[jt], 0, 0, 0);
      }
    }
    float sv[4][4];
#pragma unroll
    for (int jt = 0; jt < 4; jt++)
#pragma unroll
      for (int reg = 0; reg < 4; reg++)
        sv[jt][reg] = s[jt][reg] * 0.125f + (md[reg][jt] < 0.1f ? -1e12f : 0.0f);

    float alpha[4];
#pragma unroll
    for (int reg = 0; reg < 4; reg++) {
      float mt = fmaxf(fmaxf(sv[0][reg], sv[1][reg]), fmaxf(sv[2][reg], sv[3][reg]));
      mt = fmaxf(mt, __shfl_xor(mt, 1));
      mt = fmaxf(mt, __shfl_xor(mt, 2));
      mt = fmaxf(mt, __shfl_xor(mt, 4));
      mt = fmaxf(mt, __shfl_xor(mt, 8));
      float mn = fmaxf(m_run[reg], mt);
      alpha[reg] = __expf(m_run[reg] - mn);
      m_run[reg] = mn;
    }
#pragma unroll
    for (int reg = 0; reg < 4; reg++) {
      int row = w * 16 + g * 4 + reg;
      float ps_ = 0.0f;
#pragma unroll
      for (int jt = 0; jt < 4; jt++) {
        float p = __expf(sv[jt][reg] - m_run[reg]);
        ps_ += p;
        *(unsigned short*)(ps + SWZ(row, 2 * (jt * 16 + r))) = f2bf(p);
      }
      ps_ += __shfl_xor(ps_, 1);
      ps_ += __shfl_xor(ps_, 2);
      ps_ += __shfl_xor(ps_, 4);
      ps_ += __shfl_xor(ps_, 8);
      l_run[reg] = l_run[reg] * alpha[reg] + ps_;
    }
#pragma unroll
    for (int dt = 0; dt < 4; dt++)
#pragma unroll
      for (int reg = 0; reg < 4; reg++)
        O[dt][reg] *= alpha[reg];
    asm volatile("s_waitcnt lgkmcnt(0)" ::: "memory");
    __builtin_amdgcn_sched_barrier(0);
#pragma unroll
    for (int kc = 0; kc < 2; kc++) {
      bf16x8 aP = *(const bf16x8*)(ps + SWZ(w * 16 + r, kc * 64 + g * 16));
#pragma unroll
      for (int dt = 0; dt < 4; dt++) {
        bf16x8 bV = *(const bf16x8*)(vt + SWZ(dt * 16 + r, kc * 64 + g * 16));
        O[dt] = __builtin_amdgcn_mfma_f32_16x16x32_bf16(aP, bV, O[dt], 0, 0, 0);
      }
    }
  }
  const int bb = bh / NH, hh = bh % NH;
  float inv[4];
#pragma unroll
  for (int reg = 0; reg < 4; reg++) inv[reg] = 1.0f / l_run[reg];
  float* op = out0 + ((size_t)(bb * 1024 + qt * 64 + w * 16 + g * 4)) * 768 + hh * 64 + r;
#pragma unroll
  for (int reg = 0; reg < 4; reg++)
#pragma unroll
    for (int dt = 0; dt < 4; dt++)
      op[(size_t)reg * 768 + dt * 16] = O[dt][reg] * inv[reg];
}

// ---------------- K3: depthwise 3x3 'SAME'
__global__ __launch_bounds__(256) void k_dwconv(const float* __restrict__ y,
                                                const float* __restrict__ w1,
                                                float* __restrict__ y1) {
  const int bc = blockIdx.x;
  const int c = bc & 255;
  const float* yin = y + (size_t)bc * NPIX;
  float* yout = y1 + (size_t)bc * NPIX;
  float w[9];
#pragma unroll
  for (int i = 0; i < 9; i++) w[i] = w1[c * 9 + i];
  const int t = threadIdx.x;
#pragma unroll
  for (int rep = 0; rep < 4; rep++) {
    int px = t + rep * 256;
    int yy = px >> 5, xx = px & 31;
    float acc = 0.0f;
#pragma unroll
    for (int dy = -1; dy <= 1; dy++) {
      int sy = yy + dy;
      if (sy < 0 || sy > 31) continue;
#pragma unroll
      for (int dx = -1; dx <= 1; dx++) {
        int sx = xx + dx;
        if (sx < 0 || sx > 31) continue;
        acc = fmaf(yin[(sy << 5) + sx], w[(dy + 1) * 3 + dx + 1], acc);
      }
    }
    yout[px] = acc;
  }
}

// ---------------- K3b: y1 [b][c][p] f32 -> y1t [b][p][c] bf16
__global__ __launch_bounds__(256) void k_trans(const float* __restrict__ y1,
                                               unsigned short* __restrict__ y1t) {
  __shared__ float T[64][65];
  const int p0 = blockIdx.x * 64, c0 = blockIdx.y * 64, b = blockIdx.z;
  const int t = threadIdx.x;
  const float* src = y1 + ((size_t)b << 18);   // b*256*1024
  {
    const int pl = t & 63, cl0 = t >> 6;
#pragma unroll
    for (int i = 0; i < 16; i++) {
      int cl = cl0 * 16 + i;
      T[cl][pl] = src[(size_t)(c0 + cl) * 1024 + p0 + pl];
    }
  }
  __syncthreads();
  {
    const int cl = t & 63, pl0 = t >> 6;
    unsigned short* dst = y1t + ((size_t)b << 18);   // b*1024*256
#pragma unroll
    for (int i = 0; i < 16; i++) {
      int pl = pl0 * 16 + i;
      dst[(size_t)(p0 + pl) * 256 + c0 + cl] = f2bf(T[cl][pl]);
    }
  }
}

// ---------------- K4: 1x1 conv bf16 MFMA: C[oc][p] = W2b[768,256] x y1t[p][c]^T
// grid(8 ptiles, 6 octiles, 4 b); fused BN partial sums
__global__ __launch_bounds__(256) void k_c1x1(const unsigned short* __restrict__ W2b,
                                              const unsigned short* __restrict__ y1t,
                                              float* __restrict__ Y2,
                                              float* __restrict__ bn_sum,
                                              float* __restrict__ bn_sumsq) {
  __shared__ __align__(16) char AsB[16384];
  __shared__ __align__(16) char BsB[16384];
  const int t = threadIdx.x;
  const int w = t >> 6, l = t & 63;
  const int r = l & 15, g = l >> 4;
  const int wr = w >> 1, wc = w & 1;
  const int m0 = blockIdx.y * 128;     // oc
  const int n0 = blockIdx.x * 128;     // p
  const int b  = blockIdx.z;
  const unsigned short* Bb = y1t + ((size_t)b << 18);
  const int rsel  = l >> 3;
  const int slotp = (l & 7) ^ (rsel & 7);
  f32x4 acc[4][4] = {};

  for (int step = 0; step < 4; ++step) {
    const int k0 = step * 64;
#pragma unroll
    for (int i = 0; i < 4; i++) {
      const int chunk = (i << 2) + w;
      const int row = (chunk << 3) + rsel;
      GLOAD16(W2b + (size_t)(m0 + row) * 256 + k0 + (slotp << 3),
              AsB + (chunk << 10) + (l << 4));
      GLOAD16(Bb + (size_t)(n0 + row) * 256 + k0 + (slotp << 3),
              BsB + (chunk << 10) + (l << 4));
    }
    __syncthreads();
#pragma unroll
    for (int kk = 0; kk < 2; kk++) {
      bf16x8 a[4], bfr[4];
#pragma unroll
      for (int m = 0; m < 4; m++) {
        const int row = wr * 64 + m * 16 + r;
        a[m] = *(const bf16x8*)(AsB + SWZ(row, kk * 64 + (g << 4)));
      }
#pragma unroll
      for (int n = 0; n < 4; n++) {
        const int row = wc * 64 + n * 16 + r;
        bfr[n] = *(const bf16x8*)(BsB + SWZ(row, kk * 64 + (g << 4)));
      }
#pragma unroll
      for (int m = 0; m < 4; m++)
#pragma unroll
        for (int n = 0; n < 4; n++)
          acc[m][n] = __builtin_amdgcn_mfma_f32_16x16x32_bf16(a[m], bfr[n], acc[m][n], 0, 0, 0);
    }
    __syncthreads();
  }

  float* Yb = Y2 + (((size_t)b * DMODEL) << 10);
#pragma unroll
  for (int m = 0; m < 4; m++) {
#pragma unroll
    for (int reg = 0; reg < 4; reg++) {
      const int oc = m0 + wr * 64 + m * 16 + g * 4 + reg;
      float s = 0.0f, sq = 0.0f;
#pragma unroll
      for (int n = 0; n < 4; n++) {
        const int p = n0 + wc * 64 + n * 16 + r;
        const float val = acc[m][n][reg];
        Yb[((size_t)oc << 10) + p] = val;
        s += val;
        sq = fmaf(val, val, sq);
      }
      s  += __shfl_xor(s, 1);  sq += __shfl_xor(sq, 1);
      s  += __shfl_xor(s, 2);  sq += __shfl_xor(sq, 2);
      s  += __shfl_xor(s, 4);  sq += __shfl_xor(sq, 4);
      s  += __shfl_xor(s, 8);  sq += __shfl_xor(sq, 8);
      if (r == 0) {
        atomicAdd(&bn_sum[oc], s);
        atomicAdd(&bn_sumsq[oc], sq);
      }
    }
  }
}

// ---------------- K6: scale/shift from sums, BN+ReLU -> out1, transpose-add into out0
__global__ __launch_bounds__(256) void k_bnfuse(const float* __restrict__ y2,
                                                const float* __restrict__ bn_sum,
                                                const float* __restrict__ bn_sumsq,
                                                const float* __restrict__ gamma,
                                                const float* __restrict__ beta,
                                                float* __restrict__ out0,
                                                float* __restrict__ out1) {
  __shared__ float T[32][33];
  __shared__ float sc_l[32], sh_l[32];
  const int p0 = blockIdx.x * 32;
  const int c0 = blockIdx.y * 32;
  const int bb = blockIdx.z;
  const int tx = threadIdx.x;   // 32
  const int ty = threadIdx.y;   // 8
  const int tt = ty * 32 + tx;
  if (tt < 32) {
    const int c = c0 + tt;
    float S = bn_sum[c], SQ = bn_sumsq[c];
    float mean = S * (1.0f / 4096.0f);
    float var = SQ * (1.0f / 4096.0f) - mean * mean;
    float rstd = rsqrtf(var + 1e-5f);
    float s = gamma[c] * rstd;
    sc_l[tt] = s;
    sh_l[tt] = fmaf(-mean, s, beta[c]);
  }
  __syncthreads();
#pragma unroll
  for (int i = 0; i < 4; i++) {
    int cl = ty + 8 * i;
    int c = c0 + cl;
    size_t a = ((size_t)(bb * DMODEL + c) << 10) + p0 + tx;
    float val = fmaxf(fmaf(y2[a], sc_l[cl], sh_l[cl]), 0.0f);
    out1[a] = val;
    T[cl][tx] = val;
  }
  __syncthreads();
#pragma unroll
  for (int i = 0; i < 4; i++) {
    int pl = ty + 8 * i;
    size_t a = ((size_t)((bb << 10) + p0 + pl)) * DMODEL + c0 + tx;
    out0[a] += T[tx][pl];
  }
}

extern "C" void kernel_launch(void* const* d_in, const int* in_sizes, int n_in,
                              void* d_out, int out_size, void* d_ws, size_t ws_size,
                              hipStream_t stream) {
  (void)in_sizes; (void)n_in; (void)out_size; (void)ws_size;
  const float* x    = (const float*)d_in[0];
  const float* y    = (const float*)d_in[1];
  const float* dm   = (const float*)d_in[2];
  const float* wqkv = (const float*)d_in[3];
  const float* w1   = (const float*)d_in[4];
  const float* w2   = (const float*)d_in[5];
  const float* gam  = (const float*)d_in[6];
  const float* bet  = (const float*)d_in[7];
  float* out0 = (float*)d_out;
  float* out1 = out0 + (size_t)B_ * NTOK * DMODEL;

  char* wsb = (char*)d_ws;
  unsigned short* Xb  = (unsigned short*)wsb;                 // 6,291,456 B
  unsigned short* Wtb = (unsigned short*)(wsb + 6291456);     // 3,538,944 B
  unsigned short* W2b = (unsigned short*)(wsb + 9830400);     //   393,216 B
  unsigned short* qb  = (unsigned short*)(wsb + 10223616);    // 6,291,456 B
  unsigned short* kb  = (unsigned short*)(wsb + 16515072);
  unsigned short* vb  = (unsigned short*)(wsb + 22806528);
  unsigned short* y1t = (unsigned short*)(wsb + 29097984);    // 2,097,152 B
  float* y2 = (float*)(wsb + 31195136);                       // 12,582,912 B
  float* y1 = (float*)(wsb + 35389440);   // 4,194,304 B, inside y2 span (y1 dead before y2 written)
  float* bnacc = (float*)(wsb + 43778048);                    // 1536 floats
  float* bn_sum = bnacc;
  float* bn_sumsq = bnacc + 768;

  k_cvt<<<dim3(3361), 256, 0, stream>>>(x, wqkv, w2, Xb, Wtb, W2b, bnacc);
  k_dwconv<<<dim3(B_ * IMGC), 256, 0, stream>>>(y, w1, y1);
  k_trans<<<dim3(16, 4, B_), 256, 0, stream>>>(y1, y1t);
  k_c1x1<<<dim3(8, 6, B_), 256, 0, stream>>>(W2b, y1t, y2, bn_sum, bn_sumsq);
  k_qkv_gemm<<<dim3(18, 32), 256, 0, stream>>>(Xb, Wtb, qb, kb, vb);
  k_attn<<<dim3(48, 16), 256, 0, stream>>>(qb, kb, vb, dm, out0);
  k_bnfuse<<<dim3(32, 24, B_), dim3(32, 8), 0, stream>>>(y2, bn_sum, bn_sumsq, gam, bet, out0, out1);
}